// Round 1
// baseline (279.764 us; speedup 1.0000x reference)
//
#include <hip/hip_runtime.h>

// ---------- types ----------
typedef __attribute__((ext_vector_type(8))) _Float16 half8;
typedef __attribute__((ext_vector_type(2))) __fp16 half2r;   // cvt_pkrtz return type
typedef __attribute__((ext_vector_type(4))) float f32x4;

#define AS1 __attribute__((address_space(1)))
#define AS3 __attribute__((address_space(3)))

union H2U { half2r h; unsigned int u; };
union Frag { half8 v; unsigned long long d[2]; };

__device__ __forceinline__ unsigned int pk(float a, float b) {
    H2U x; x.h = __builtin_amdgcn_cvt_pkrtz(a, b); return x.u;
}

__device__ __forceinline__ void gload_lds16(const void* g, void* l) {
    __builtin_amdgcn_global_load_lds((const AS1 unsigned int*)g,
                                     (AS3 unsigned int*)l, 16, 0, 0);
}

// ---------- problem constants ----------
// M = B*T = 32768, D_STATE = 1088, D_MODEL = 1024, D_LATENT = 128
#define W1_ROWB 2176           // 17 slabs * 128 B per row (f16, swizzled)
#define WS2_OFF 2228224        // 1024 * 2176
#define W2_ROWB 256            // 2 slabs * 128 B
#define A_ROWB  2176           // Af16 row: same slab layout as W_read
#define WS2_SZ  524288         // 2048 * 256
#define A16_SZ  71303168ull    // 32768 * 2176

// pick the fused-add source for k-step ks
__device__ __forceinline__ void pick_w(int ks, const float* wsp, const float* whp,
                                       const float* whs, const float* wtg,
                                       const float*& wbase, int& wstr, int& wko) {
    if (ks < 8)       { wbase = wsp; wstr = 512; wko = ks * 64; }
    else if (ks < 12) { wbase = whp; wstr = 256; wko = ks * 64 - 512; }
    else if (ks < 16) { wbase = whs; wstr = 256; wko = ks * 64 - 768; }
    else              { wbase = wtg; wstr = 64;  wko = 0; }
}

// ============ merged prologue: fuse_a (34816 blocks) + prep_w (1344 blocks) ====
// fuse_a: Af16[m][k] = cvt(S + w), pre-swizzled slabs.
//   layout: row n, byte = n*ROWB + (k/64)*128 + ((2*(k%64)) ^ ((n&7)<<4))
// prep_w: W_read / Wk|Wv -> f16, same swizzle.
__global__ __launch_bounds__(256)
void prep_fuse(const float* __restrict__ S, const float* __restrict__ wsp,
               const float* __restrict__ whp, const float* __restrict__ whs,
               const float* __restrict__ wtg, char* __restrict__ a16,
               const float* __restrict__ Wr, const float* __restrict__ Wk,
               const float* __restrict__ Wv, char* __restrict__ ws) {
    int bid = blockIdx.x;
    int tid = threadIdx.x;
    if (bid < 34816) {
        // ---- fuse_a: unit = one uint2 (4 f32 -> 4 f16). 32768 rows * 272 units
        int u = bid * 256 + tid;
        int row = u / 272;
        int rem = u % 272;
        int ks = rem >> 4;
        int k4 = (rem & 15) << 2;                    // 0..60 within slab

        const float* wbase; int wstr, wko;
        pick_w(ks, wsp, whp, whs, wtg, wbase, wstr, wko);

        f32x4 s4 = *(const f32x4*)(S + (size_t)row * 1088 + ks * 64 + k4);
        f32x4 w4 = *(const f32x4*)(wbase + (size_t)row * wstr + wko + k4);
        uint2 q; q.x = pk(s4.x + w4.x, s4.y + w4.y);
                 q.y = pk(s4.z + w4.z, s4.w + w4.w);
        size_t off = (size_t)row * A_ROWB + (ks << 7)
                   + (((k4) << 1) ^ ((row & 7) << 4));
        *(uint2*)(a16 + off) = q;
    } else {
        // ---- prep_w
        int id = (bid - 34816) * 256 + tid;
        if (id < 272 * 1024) {                       // W_read: 1024 x 1088
            int n = id / 272;
            int k = (id % 272) * 4;
            f32x4 w = *(const f32x4*)(Wr + (size_t)n * 1088 + k);
            uint2 q; q.x = pk(w.x, w.y); q.y = pk(w.z, w.w);
            size_t off = (size_t)n * W1_ROWB + ((k >> 6) << 7)
                       + (((k & 63) << 1) ^ ((n & 7) << 4));
            *(uint2*)(ws + off) = q;
        } else {                                     // Wk|Wv combined: 2048 x 128
            int j = id - 272 * 1024;                 // grid sized exactly
            int r = j >> 5;                          // 0..2047
            int k = (j & 31) << 2;                   // 0..124
            const float* src = (r < 1024) ? (Wk + (size_t)r * 128 + k)
                                          : (Wv + (size_t)(r - 1024) * 128 + k);
            f32x4 w = *(const f32x4*)src;
            uint2 q; q.x = pk(w.x, w.y); q.y = pk(w.z, w.w);
            size_t off = WS2_OFF + (size_t)r * W2_ROWB + ((k >> 6) << 7)
                       + (((k & 63) << 1) ^ ((r & 7) << 4));
            *(uint2*)(ws + off) = q;
        }
    }
}

// ============ GEMM1 body: out = Af16 @ W_read^T (idx in [0,2048)) ============
__device__ __forceinline__
void body_read(int idx, const char* __restrict__ wsA, const char* __restrict__ wws,
               float* __restrict__ out, char* lds) {
    // A0=lds, A1=+16384, B0=+32768, B1=+49152
    int wg   = (idx & 7) * 256 + (idx >> 3);     // bijective XCD swizzle (2048%8==0)
    int mblk = wg >> 3, nblk = wg & 7;
    int m0 = mblk << 7, n0 = nblk << 7;

    int tid = threadIdx.x;
    int lane = tid & 63, wid = tid >> 6;
    int wm = (wid >> 1) << 6, wn = (wid & 1) << 6;   // wave sub-tile origin
    int lp = lane & 15, lg = lane >> 4;

    f32x4 acc[4][4] = {};

#define STAGE_T(KS, DL, BASE, ROWB, R0) do {                              \
        const char* grow = (BASE) + (size_t)(R0) * (ROWB) + (KS) * 128;   \
        _Pragma("unroll")                                                 \
        for (int c = 0; c < 4; ++c) {                                     \
            int s = c * 4096 + wid * 1024 + lane * 16;                    \
            int rr = s >> 7, cb = s & 127;                                \
            gload_lds16(grow + (size_t)rr * (ROWB) + cb,                  \
                        (DL) + c * 4096 + wid * 1024);                    \
        }                                                                 \
    } while (0)

#define COMPUTE(AL, BL) do {                                              \
        _Pragma("unroll")                                                 \
        for (int b = 0; b < 2; ++b) {                                     \
            Frag af[4], bf[4];                                            \
            _Pragma("unroll")                                             \
            for (int f = 0; f < 4; ++f) {                                 \
                int ra = wm + f * 16 + lp;  int xa = (ra & 7) << 4;       \
                af[f].d[0] = *(const unsigned long long*)((AL) + (ra << 7) + ((b * 64 + lg * 8) ^ xa));      \
                af[f].d[1] = *(const unsigned long long*)((AL) + (ra << 7) + ((b * 64 + 32 + lg * 8) ^ xa)); \
                int rb = wn + f * 16 + lp;  int xb = (rb & 7) << 4;       \
                bf[f].d[0] = *(const unsigned long long*)((BL) + (rb << 7) + ((b * 64 + lg * 8) ^ xb));      \
                bf[f].d[1] = *(const unsigned long long*)((BL) + (rb << 7) + ((b * 64 + 32 + lg * 8) ^ xb)); \
            }                                                             \
            _Pragma("unroll")                                             \
            for (int i = 0; i < 4; ++i)                                   \
                _Pragma("unroll")                                         \
                for (int j = 0; j < 4; ++j)                               \
                    acc[i][j] = __builtin_amdgcn_mfma_f32_16x16x32_f16(af[i].v, bf[j].v, acc[i][j], 0, 0, 0); \
        }                                                                 \
    } while (0)

    // prologue: fill buffer 0
    STAGE_T(0, lds,         wsA, A_ROWB,  m0);
    STAGE_T(0, lds + 32768, wws, W1_ROWB, n0);
    __syncthreads();

    for (int ks = 0; ks < 17; ++ks) {
        int co = (ks & 1) ? 16384 : 0;
        int no = co ^ 16384;
        if (ks < 16) {
            STAGE_T(ks + 1, lds + no,         wsA, A_ROWB,  m0);
            STAGE_T(ks + 1, lds + 32768 + no, wws, W1_ROWB, n0);
        }
        COMPUTE(lds + co, lds + 32768 + co);
        __syncthreads();
    }

    // epilogue: C[row = wm+i*16+lg*4+r][col = wn+j*16+lp]
    #pragma unroll
    for (int i = 0; i < 4; ++i)
        #pragma unroll
        for (int j = 0; j < 4; ++j) {
            int row = m0 + wm + i * 16 + (lg << 2);
            int col = n0 + wn + j * 16 + lp;
            float* p = out + (size_t)row * 1024 + col;
            #pragma unroll
            for (int r = 0; r < 4; ++r) p[(size_t)r * 1024] = acc[i][j][r];
        }
#undef STAGE_T
#undef COMPUTE
}

// ============ GEMM2 body: k|v = latent @ (Wk|Wv)^T ============
// idx in [0, nkv); nkv8 = nkv/8; nb = nb_off + (wg & nb_mask)
__device__ __forceinline__
void body_kv(int idx, int nkv8, int nb_shift, int nb_mask, int nb_off,
             const float* __restrict__ lat, const char* __restrict__ ws2,
             float* __restrict__ outk, float* __restrict__ outv, char* lds) {
    char* Al = lds;
    char* Bl = lds + 16384;

    int wg   = (idx & 7) * nkv8 + (idx >> 3);    // bijective XCD swizzle (nkv%8==0)
    int mblk = wg >> nb_shift, nb = nb_off + (wg & nb_mask);
    int m0 = mblk << 7;
    int nrow0 = nb << 7;                          // row in combined Wk|Wv
    float* out = (nb < 8) ? outk : outv;
    int n0 = (nb & 7) << 7;

    int tid = threadIdx.x;
    int lane = tid & 63, wid = tid >> 6;
    int wm = (wid >> 1) << 6, wn = (wid & 1) << 6;
    int lp = lane & 15, lg = lane >> 4;

    f32x4 acc[4][4] = {};

    for (int ks = 0; ks < 2; ++ks) {
        __syncthreads();
        {
            const char* wrow = ws2 + (size_t)nrow0 * W2_ROWB + ks * 128;
            #pragma unroll
            for (int c = 0; c < 4; ++c) {
                int s = c * 4096 + wid * 1024 + lane * 16;
                int n = s >> 7, cb = s & 127;
                gload_lds16(wrow + (size_t)n * W2_ROWB + cb,
                            Bl + c * 4096 + wid * 1024);
            }
        }
        #pragma unroll
        for (int i = 0; i < 8; ++i) {
            int u = i * 256 + tid;
            int row = u >> 4;
            int k4 = (u & 15) << 2;
            f32x4 s4 = *(const f32x4*)(lat + (size_t)(m0 + row) * 128 + ks * 64 + k4);
            uint2 q; q.x = pk(s4.x, s4.y); q.y = pk(s4.z, s4.w);
            *(uint2*)(Al + (row << 7) + ((k4 << 1) ^ ((row & 7) << 4))) = q;
        }
        __syncthreads();

        #pragma unroll
        for (int b = 0; b < 2; ++b) {
            Frag af[4], bf[4];
            #pragma unroll
            for (int f = 0; f < 4; ++f) {
                int ra = wm + f * 16 + lp;  int xa = (ra & 7) << 4;
                af[f].d[0] = *(const unsigned long long*)(Al + (ra << 7) + ((b * 64 + lg * 8) ^ xa));
                af[f].d[1] = *(const unsigned long long*)(Al + (ra << 7) + ((b * 64 + 32 + lg * 8) ^ xa));
                int rb = wn + f * 16 + lp;  int xb = (rb & 7) << 4;
                bf[f].d[0] = *(const unsigned long long*)(Bl + (rb << 7) + ((b * 64 + lg * 8) ^ xb));
                bf[f].d[1] = *(const unsigned long long*)(Bl + (rb << 7) + ((b * 64 + 32 + lg * 8) ^ xb));
            }
            #pragma unroll
            for (int i = 0; i < 4; ++i)
                #pragma unroll
                for (int j = 0; j < 4; ++j)
                    acc[i][j] = __builtin_amdgcn_mfma_f32_16x16x32_f16(af[i].v, bf[j].v, acc[i][j], 0, 0, 0);
        }
    }

    #pragma unroll
    for (int i = 0; i < 4; ++i)
        #pragma unroll
        for (int j = 0; j < 4; ++j) {
            int row = m0 + wm + i * 16 + (lg << 2);
            int col = n0 + wn + j * 16 + lp;
            float* p = out + (size_t)row * 1024 + col;
            #pragma unroll
            for (int r = 0; r < 4; ++r) p[(size_t)r * 1024] = acc[i][j][r];
        }
}

// ============ merged GEMM: 2048 read-blocks + 4096 kv-blocks, 1:2 interleave ==
// Group-of-8 role assignment keeps idx%8 == bid%8, preserving each role's
// XCD-chunk swizzle AND putting both roles on every XCD (MFMA || HBM-write overlap).
__global__ __launch_bounds__(256, 2)
void gemm_all(const char* __restrict__ wsA, const char* __restrict__ wws,
              float* __restrict__ out, const float* __restrict__ lat,
              const char* __restrict__ ws2,
              float* __restrict__ outk, float* __restrict__ outv) {
    __shared__ char lds[65536];
    int bid = blockIdx.x;
    int g = bid >> 3, o = bid & 7;
    int gq = g / 3, gm = g % 3;
    if (gm == 0)
        body_read(gq * 8 + o, wsA, wws, out, lds);
    else
        body_kv((gq * 2 + (gm - 1)) * 8 + o, 512, 4, 15, 0, lat, ws2, outk, outv, lds);
}

// fallback: read + k-half only (no overlap with a16-in-v-region), 1:1 interleave
__global__ __launch_bounds__(256, 2)
void gemm_rk(const char* __restrict__ wsA, const char* __restrict__ wws,
             float* __restrict__ out, const float* __restrict__ lat,
             const char* __restrict__ ws2, float* __restrict__ outk) {
    __shared__ char lds[65536];
    int bid = blockIdx.x;
    int g = bid >> 3, o = bid & 7;
    if ((g & 1) == 0)
        body_read((g >> 1) * 8 + o, wsA, wws, out, lds);
    else
        body_kv((g >> 1) * 8 + o, 256, 3, 7, 0, lat, ws2, outk, outk, lds);
}

// fallback: v-half (runs after gemm_rk; overwrites the a16 region safely)
__global__ __launch_bounds__(256, 2)
void gemm_v(const float* __restrict__ lat, const char* __restrict__ ws2,
            float* __restrict__ outk, float* __restrict__ outv) {
    __shared__ char lds[32768];
    body_kv(blockIdx.x, 256, 3, 7, 8, lat, ws2, outk, outv, lds);
}

// ============ host ============
extern "C" void kernel_launch(void* const* d_in, const int* in_sizes, int n_in,
                              void* d_out, int out_size, void* d_ws, size_t ws_size,
                              hipStream_t stream) {
    const float* S   = (const float*)d_in[0];
    const float* wsp = (const float*)d_in[1];
    const float* whp = (const float*)d_in[2];
    const float* whs = (const float*)d_in[3];
    const float* wtg = (const float*)d_in[4];
    const float* Wr  = (const float*)d_in[5];
    // d_in[6] = cache: fully overwritten by latent -> dead input
    const float* lat = (const float*)d_in[7];
    const float* Wk  = (const float*)d_in[8];
    const float* Wv  = (const float*)d_in[9];
    float* out = (float*)d_out;
    char*  ws  = (char*)d_ws;

    float* outk = out + 33554432ull;
    float* outv = out + 67108864ull;

    const size_t A16_WS_OFF = (size_t)WS2_OFF + WS2_SZ;   // 2,752,512
    const size_t ws_need = A16_WS_OFF + A16_SZ;           // ~74 MB

    if (ws_size >= ws_need) {
        // a16 in dedicated workspace -> full read||kv overlap is race-free
        char* a16 = ws + A16_WS_OFF;
        hipLaunchKernelGGL(prep_fuse, dim3(36160), dim3(256), 0, stream,
                           S, wsp, whp, whs, wtg, a16, Wr, Wk, Wv, ws);
        hipLaunchKernelGGL(gemm_all, dim3(6144), dim3(256), 0, stream,
                           a16, ws, out, lat, ws + WS2_OFF, outk, outv);
    } else {
        // a16 aliases the v output region: overlap only read || k-half, then v
        char* a16 = (char*)outv;
        hipLaunchKernelGGL(prep_fuse, dim3(36160), dim3(256), 0, stream,
                           S, wsp, whp, whs, wtg, a16, Wr, Wk, Wv, ws);
        hipLaunchKernelGGL(gemm_rk, dim3(4096), dim3(256), 0, stream,
                           a16, ws, out, lat, ws + WS2_OFF, outk);
        hipLaunchKernelGGL(gemm_v, dim3(2048), dim3(256), 0, stream,
                           lat, ws + WS2_OFF, outk, outv);
    }
}